// Round 1
// baseline (535.277 us; speedup 1.0000x reference)
//
#include <hip/hip_runtime.h>
#include <cstdint>

// Instant-NGP hash-grid embedder.
// B=524288 points, 16 levels, 2 feats/level, 2^19 entries/level.
// Output layout: out[b*32 + feat*16 + level]  (reference transposes (1,2,0)).
//
// Discrete steps (bottom_left trunc) replicated in float64 to match the
// NumPy reference under NEP-50 promotion (f64 scalar `b` promotes
// resolution/grid_size/quotient chain to f64). Resolutions hardcoded to the
// exact-math floor(16 * 2^(l/3)) values.

constexpr int NLEV = 16;
constexpr uint32_t HM_MASK = (1u << 19) - 1;

__device__ __constant__ double c_res[NLEV] = {
    16.0, 20.0, 25.0, 32.0, 40.0, 50.0, 64.0, 80.0,
    101.0, 128.0, 161.0, 203.0, 256.0, 322.0, 406.0, 512.0
};

__global__ __launch_bounds__(256)
void ngp_embed_kernel(const float* __restrict__ x,
                      const float* __restrict__ table,
                      const float* __restrict__ box_min,
                      const float* __restrict__ box_max,
                      float* __restrict__ out,
                      int B)
{
    const int gid = blockIdx.x * 256 + threadIdx.x;
    const int b = gid >> 4;       // point index
    const int l = gid & 15;       // level index
    if (b >= B) return;

    // Box (uniform across threads; L1 broadcast)
    const float bm0 = box_min[0], bm1 = box_min[1], bm2 = box_min[2];
    const float d0 = box_max[0] - bm0;
    const float d1 = box_max[1] - bm1;
    const float d2 = box_max[2] - bm2;

    const float fx0 = x[3 * b + 0];
    const float fx1 = x[3 * b + 1];
    const float fx2 = x[3 * b + 2];

    const double res = c_res[l];
    // grid_size in f64, exactly as np: (f32 diff) / (f64 res)
    const double g0 = (double)d0 / res;
    const double g1 = (double)d1 / res;
    const double g2 = (double)d2 / res;
    // quotient in f64: (f32 (x - bmin)) / g  — discrete-critical
    const double q0 = (double)(fx0 - bm0) / g0;
    const double q1 = (double)(fx1 - bm1) / g1;
    const double q2 = (double)(fx2 - bm2) / g2;
    const int i0 = (int)q0;   // trunc toward zero == np astype(int32), q>=0
    const int i1 = (int)q1;
    const int i2 = (int)q2;
    // weights: continuous, large tolerance — f32 is plenty
    const float w0 = (float)(q0 - (double)i0);
    const float w1 = (float)(q1 - (double)i1);
    const float w2 = (float)(q2 - (double)i2);

    // NGP hash: primes {1, 2654435761, 805459861}, uint32 wraparound
    const uint32_t P1 = 2654435761u, P2 = 805459861u;
    const uint32_t h0a = (uint32_t)i0;
    const uint32_t h0b = h0a + 1u;
    const uint32_t h1a = (uint32_t)i1 * P1;
    const uint32_t h1b = h1a + P1;
    const uint32_t h2a = (uint32_t)i2 * P2;
    const uint32_t h2b = h2a + P2;
    const uint32_t base = (uint32_t)l << 19;

    const float2* __restrict__ tab2 = (const float2*)table;
    // vXYZ : X = offset in dim0 (i), Y = dim1 (j), Z = dim2 (k)
    const float2 v000 = tab2[base + ((h0a ^ h1a ^ h2a) & HM_MASK)];
    const float2 v001 = tab2[base + ((h0a ^ h1a ^ h2b) & HM_MASK)];
    const float2 v010 = tab2[base + ((h0a ^ h1b ^ h2a) & HM_MASK)];
    const float2 v011 = tab2[base + ((h0a ^ h1b ^ h2b) & HM_MASK)];
    const float2 v100 = tab2[base + ((h0b ^ h1a ^ h2a) & HM_MASK)];
    const float2 v101 = tab2[base + ((h0b ^ h1a ^ h2b) & HM_MASK)];
    const float2 v110 = tab2[base + ((h0b ^ h1b ^ h2a) & HM_MASK)];
    const float2 v111 = tab2[base + ((h0b ^ h1b ^ h2b) & HM_MASK)];

    const float u0 = 1.0f - w0, u1 = 1.0f - w1, u2 = 1.0f - w2;
    const float waa = u1 * u2;   // j=0,k=0
    const float wab = u1 * w2;   // j=0,k=1
    const float wba = w1 * u2;   // j=1,k=0
    const float wbb = w1 * w2;   // j=1,k=1

    const float f0 = u0 * (waa * v000.x + wab * v001.x + wba * v010.x + wbb * v011.x)
                   + w0 * (waa * v100.x + wab * v101.x + wba * v110.x + wbb * v111.x);
    const float f1 = u0 * (waa * v000.y + wab * v001.y + wba * v010.y + wbb * v011.y)
                   + w0 * (waa * v100.y + wab * v101.y + wba * v110.y + wbb * v111.y);

    // out[b, feat*16 + level]
    out[b * 32 + l]      = f0;
    out[b * 32 + 16 + l] = f1;
}

extern "C" void kernel_launch(void* const* d_in, const int* in_sizes, int n_in,
                              void* d_out, int out_size, void* d_ws, size_t ws_size,
                              hipStream_t stream) {
    const float* x       = (const float*)d_in[0];
    const float* table   = (const float*)d_in[1];
    const float* box_min = (const float*)d_in[2];
    const float* box_max = (const float*)d_in[3];
    float* out = (float*)d_out;

    const int B = in_sizes[0] / 3;
    const int total = B * NLEV;
    const int blocks = (total + 255) / 256;
    hipLaunchKernelGGL(ngp_embed_kernel, dim3(blocks), dim3(256), 0, stream,
                       x, table, box_min, box_max, out, B);
}

// Round 2
// 345.462 us; speedup vs baseline: 1.5495x; 1.5495x over previous
//
#include <hip/hip_runtime.h>
#include <cstdint>

// Instant-NGP hash-grid embedder, 2-phase with level->XCD affinity.
//
// Phase A: one block = one level x 256 points. blockIdx%8 pins level pairs
//   (i, 15-i) to one XCD residue (HW round-robin dispatch heuristic), coarse
//   phase first then fine, so each XCD's 4MB L2 holds exactly the active
//   level slab -> gathers hit L2 instead of fetching 64B lines per 8B read.
//   Writes level-major float2 to ws (coalesced).
// Phase B: streaming transpose ws[l][b] -> out[b][f*16+l]; thread-per-point,
//   16 coalesced float2 loads + 8 contiguous float4 stores.
//
// Discrete steps (bottom_left trunc) replicated in float64 to match the
// NumPy reference under NEP-50 promotion. Resolutions hardcoded to the
// exact-math floor(16 * 2^(l/3)) values.

constexpr int NLEV = 16;
constexpr uint32_t HM_MASK = (1u << 19) - 1;

__device__ __constant__ double c_res[NLEV] = {
    16.0, 20.0, 25.0, 32.0, 40.0, 50.0, 64.0, 80.0,
    101.0, 128.0, 161.0, 203.0, 256.0, 322.0, 406.0, 512.0
};

__device__ __forceinline__ void ngp_eval_point(
    int b, int lev,
    const float* __restrict__ x,
    const float2* __restrict__ tab2,
    float bm0, float bm1, float bm2,
    float d0, float d1, float d2,
    float& f0, float& f1)
{
    const float fx0 = x[3 * b + 0];
    const float fx1 = x[3 * b + 1];
    const float fx2 = x[3 * b + 2];

    const double res = c_res[lev];
    const double g0 = (double)d0 / res;
    const double g1 = (double)d1 / res;
    const double g2 = (double)d2 / res;
    const double q0 = (double)(fx0 - bm0) / g0;
    const double q1 = (double)(fx1 - bm1) / g1;
    const double q2 = (double)(fx2 - bm2) / g2;
    const int i0 = (int)q0;
    const int i1 = (int)q1;
    const int i2 = (int)q2;
    const float w0 = (float)(q0 - (double)i0);
    const float w1 = (float)(q1 - (double)i1);
    const float w2 = (float)(q2 - (double)i2);

    const uint32_t P1 = 2654435761u, P2 = 805459861u;
    const uint32_t h0a = (uint32_t)i0;
    const uint32_t h0b = h0a + 1u;
    const uint32_t h1a = (uint32_t)i1 * P1;
    const uint32_t h1b = h1a + P1;
    const uint32_t h2a = (uint32_t)i2 * P2;
    const uint32_t h2b = h2a + P2;
    const uint32_t base = (uint32_t)lev << 19;

    const float2 v000 = tab2[base + ((h0a ^ h1a ^ h2a) & HM_MASK)];
    const float2 v001 = tab2[base + ((h0a ^ h1a ^ h2b) & HM_MASK)];
    const float2 v010 = tab2[base + ((h0a ^ h1b ^ h2a) & HM_MASK)];
    const float2 v011 = tab2[base + ((h0a ^ h1b ^ h2b) & HM_MASK)];
    const float2 v100 = tab2[base + ((h0b ^ h1a ^ h2a) & HM_MASK)];
    const float2 v101 = tab2[base + ((h0b ^ h1a ^ h2b) & HM_MASK)];
    const float2 v110 = tab2[base + ((h0b ^ h1b ^ h2a) & HM_MASK)];
    const float2 v111 = tab2[base + ((h0b ^ h1b ^ h2b) & HM_MASK)];

    const float u0 = 1.0f - w0, u1 = 1.0f - w1, u2 = 1.0f - w2;
    const float waa = u1 * u2;
    const float wab = u1 * w2;
    const float wba = w1 * u2;
    const float wbb = w1 * w2;

    f0 = u0 * (waa * v000.x + wab * v001.x + wba * v010.x + wbb * v011.x)
       + w0 * (waa * v100.x + wab * v101.x + wba * v110.x + wbb * v111.x);
    f1 = u0 * (waa * v000.y + wab * v001.y + wba * v010.y + wbb * v011.y)
       + w0 * (waa * v100.y + wab * v101.y + wba * v110.y + wbb * v111.y);
}

// ---------------- Phase A: per-level gather+interp, level-major ws ----------
__global__ __launch_bounds__(256)
void ngp_levels_kernel(const float* __restrict__ x,
                       const float* __restrict__ table,
                       const float* __restrict__ box_min,
                       const float* __restrict__ box_max,
                       float2* __restrict__ ws,
                       int B, int chunks)
{
    // XCD-affinity mapping: residue = blockIdx%8 -> XCD (HW round-robin).
    // XCD residue i handles level i (phase 1, coarse) then 15-i (phase 2, fine).
    const int xcd = blockIdx.x & 7;
    const int s   = blockIdx.x >> 3;
    const int lev   = (s < chunks) ? xcd : (15 - xcd);
    const int chunk = (s < chunks) ? s : (s - chunks);
    const int b = chunk * 256 + threadIdx.x;
    if (b >= B) return;

    const float bm0 = box_min[0], bm1 = box_min[1], bm2 = box_min[2];
    const float d0 = box_max[0] - bm0;
    const float d1 = box_max[1] - bm1;
    const float d2 = box_max[2] - bm2;

    float f0, f1;
    ngp_eval_point(b, lev, x, (const float2*)table,
                   bm0, bm1, bm2, d0, d1, d2, f0, f1);

    ws[(size_t)lev * B + b] = make_float2(f0, f1);  // coalesced 8B
}

// ---------------- Phase B: transpose ws[l][b] -> out[b][f*16+l] -------------
__global__ __launch_bounds__(256)
void ngp_transpose_kernel(const float2* __restrict__ ws,
                          float* __restrict__ out,
                          int B)
{
    const int b = blockIdx.x * 256 + threadIdx.x;
    if (b >= B) return;

    float2 v[NLEV];
#pragma unroll
    for (int l = 0; l < NLEV; ++l)
        v[l] = ws[(size_t)l * B + b];   // coalesced per level across the wave

    float4* __restrict__ o4 = (float4*)(out + (size_t)b * 32);
#pragma unroll
    for (int i = 0; i < 4; ++i)
        o4[i] = make_float4(v[4*i].x, v[4*i+1].x, v[4*i+2].x, v[4*i+3].x);
#pragma unroll
    for (int i = 0; i < 4; ++i)
        o4[4 + i] = make_float4(v[4*i].y, v[4*i+1].y, v[4*i+2].y, v[4*i+3].y);
}

// ---------------- Fallback: original fused kernel (if ws too small) ---------
__global__ __launch_bounds__(256)
void ngp_embed_fused_kernel(const float* __restrict__ x,
                            const float* __restrict__ table,
                            const float* __restrict__ box_min,
                            const float* __restrict__ box_max,
                            float* __restrict__ out,
                            int B)
{
    const int gid = blockIdx.x * 256 + threadIdx.x;
    const int b = gid >> 4;
    const int l = gid & 15;
    if (b >= B) return;

    const float bm0 = box_min[0], bm1 = box_min[1], bm2 = box_min[2];
    const float d0 = box_max[0] - bm0;
    const float d1 = box_max[1] - bm1;
    const float d2 = box_max[2] - bm2;

    float f0, f1;
    ngp_eval_point(b, l, x, (const float2*)table,
                   bm0, bm1, bm2, d0, d1, d2, f0, f1);

    out[b * 32 + l]      = f0;
    out[b * 32 + 16 + l] = f1;
}

extern "C" void kernel_launch(void* const* d_in, const int* in_sizes, int n_in,
                              void* d_out, int out_size, void* d_ws, size_t ws_size,
                              hipStream_t stream) {
    const float* x       = (const float*)d_in[0];
    const float* table   = (const float*)d_in[1];
    const float* box_min = (const float*)d_in[2];
    const float* box_max = (const float*)d_in[3];
    float* out = (float*)d_out;

    const int B = in_sizes[0] / 3;
    const size_t ws_needed = (size_t)B * NLEV * sizeof(float2);

    if (ws_size >= ws_needed) {
        const int chunks = (B + 255) / 256;
        const int gridA = 8 * 2 * chunks;   // 8 residues x 2 levels x chunks
        hipLaunchKernelGGL(ngp_levels_kernel, dim3(gridA), dim3(256), 0, stream,
                           x, table, box_min, box_max, (float2*)d_ws, B, chunks);
        const int gridB = (B + 255) / 256;
        hipLaunchKernelGGL(ngp_transpose_kernel, dim3(gridB), dim3(256), 0, stream,
                           (const float2*)d_ws, out, B);
    } else {
        const int total = B * NLEV;
        const int blocks = (total + 255) / 256;
        hipLaunchKernelGGL(ngp_embed_fused_kernel, dim3(blocks), dim3(256), 0, stream,
                           x, table, box_min, box_max, out, B);
    }
}